// Round 2
// baseline (156.954 us; speedup 1.0000x reference)
//
#include <hip/hip_runtime.h>
#include <hip/hip_bf16.h>
#include <math.h>

#define Nn 4096
#define Hdim 256
#define Edim 128
#define Cdim 32
#define Vdim 64
#define Kdim 20
#define G4H 1024
#define OUTS 513

// bucketing
#define SK 512
#define SC 256
#define RK_OFF 64
#define RC_OFF (RK_OFF + Kdim * SK)      // 10304 (ints); ends at 18496 ints = 73984 B

// bf16 fragment arrays in workspace (byte offsets)
#define OFF_WF 81920
#define WF_BYTES (Kdim * 4 * 12 * 16 * 64 * 8 * 2)   // 15,728,640
#define OFF_XF (OFF_WF + WF_BYTES)
#define XF_BYTES (Kdim * 8 * 12 * 4 * 64 * 8 * 2)    // 7,864,320
#define OFF_LF (OFF_XF + XF_BYTES)
#define LF_BYTES (Cdim * 8 * 5 * 64 * 8 * 2)         // 1,310,720
#define OFF_VF (OFF_LF + LF_BYTES)
#define VF_BYTES (Cdim * 8 * 8 * 2 * 64 * 8 * 2)     // 4,194,304

// grids
#define NWF (Kdim * 4 * 12)          // 960
#define NXF (Kdim * 8)               // 160
#define NLF (Cdim * 8)               // 256
#define NVF (Cdim * 8)               // 256
#define FRAG_GRID (NWF + NXF + NLF + NVF)   // 1632

#define LSTM_BLOCKS (Kdim * 8 * 4)   // 640
#define LOSS_BLOCKS (Cdim * 8)       // 256
#define MAIN_GRID (LSTM_BLOCKS + LOSS_BLOCKS)  // 896

typedef short bf16x8 __attribute__((ext_vector_type(8)));
typedef float f32x4 __attribute__((ext_vector_type(4)));
typedef unsigned short u16;

__device__ __forceinline__ float sigmoidf_(float x) { return 1.0f / (1.0f + expf(-x)); }

__device__ __forceinline__ bf16x8 cvt8(float4 f0, float4 f1) {
    bf16x8 r;
    __hip_bfloat16 h;
    h = __float2bfloat16(f0.x); r[0] = *(short*)&h;
    h = __float2bfloat16(f0.y); r[1] = *(short*)&h;
    h = __float2bfloat16(f0.z); r[2] = *(short*)&h;
    h = __float2bfloat16(f0.w); r[3] = *(short*)&h;
    h = __float2bfloat16(f1.x); r[4] = *(short*)&h;
    h = __float2bfloat16(f1.y); r[5] = *(short*)&h;
    h = __float2bfloat16(f1.z); r[6] = *(short*)&h;
    h = __float2bfloat16(f1.w); r[7] = *(short*)&h;
    return r;
}

// ================= setup 1: bucket rows by cell_id / category =================
__global__ __launch_bounds__(1024) void k_bucket(const int* __restrict__ cell_id,
                                                 const int* __restrict__ category,
                                                 int* __restrict__ ws) {
    __shared__ int cnt[32];
    int t = threadIdx.x;
    if (t < 32) cnt[t] = 0;
    __syncthreads();
    int i0 = t * 4;
    if (blockIdx.x == 0) {
        int4 v = ((const int4*)cell_id)[t];
        int r;
        r = atomicAdd(&cnt[v.x], 1); if (r < SK) ws[RK_OFF + v.x * SK + r] = i0 + 0;
        r = atomicAdd(&cnt[v.y], 1); if (r < SK) ws[RK_OFF + v.y * SK + r] = i0 + 1;
        r = atomicAdd(&cnt[v.z], 1); if (r < SK) ws[RK_OFF + v.z * SK + r] = i0 + 2;
        r = atomicAdd(&cnt[v.w], 1); if (r < SK) ws[RK_OFF + v.w * SK + r] = i0 + 3;
        __syncthreads();
        if (t < 32) ws[t] = min(cnt[t], SK);
    } else {
        int4 v = ((const int4*)category)[t];
        int r;
        r = atomicAdd(&cnt[v.x], 1); if (r < SC) ws[RC_OFF + v.x * SC + r] = i0 + 0;
        r = atomicAdd(&cnt[v.y], 1); if (r < SC) ws[RC_OFF + v.y * SC + r] = i0 + 1;
        r = atomicAdd(&cnt[v.z], 1); if (r < SC) ws[RC_OFF + v.z * SC + r] = i0 + 2;
        r = atomicAdd(&cnt[v.w], 1); if (r < SC) ws[RC_OFF + v.w * SC + r] = i0 + 3;
        __syncthreads();
        if (t < 32) ws[32 + t] = min(cnt[t], SC);
    }
}

// ================= setup 2: build bf16 fragment panels =================
// Fragment convention (mfma_f32_16x16x32_bf16): lane l = 16*q + r holds
// M[row r][k = 8q .. 8q+7] as 8 bf16 (16 B), stored at chunk*1KB + l*16B.
__global__ __launch_bounds__(256) void k_frag(
    const float* __restrict__ W_ih, const float* __restrict__ W_hh,
    const float* __restrict__ Wlin, const float* __restrict__ Wec, const float* __restrict__ Wrel,
    const float* __restrict__ inp, const float* __restrict__ h_prev, const float* __restrict__ vec,
    int* __restrict__ ws)
{
    u16* WF = (u16*)((char*)ws + OFF_WF);
    u16* XF = (u16*)((char*)ws + OFF_XF);
    u16* LF = (u16*)((char*)ws + OFF_LF);
    u16* VF = (u16*)((char*)ws + OFF_VF);
    int b = blockIdx.x, t = threadIdx.x;
    int l = t & 63, sub = t >> 6;
    int c16 = l & 15, qd = l >> 4;

    if (b < NWF) {
        // ---- LSTM weight fragments: (k, hq, st) ----
        int k = b / 48; int r = b - k * 48; int hq = r / 12; int st = r - hq * 12;
        int kk = st * 32 + qd * 8;
        #pragma unroll
        for (int rep = 0; rep < 4; rep++) {
            int idx = sub * 4 + rep;           // = g*4 + wv
            int g = idx >> 2, wv = idx & 3;
            int row = g * Hdim + hq * 64 + wv * 16 + c16;   // row in 4H
            const float* p = (st < 4)
                ? (W_ih + ((size_t)k * G4H + row) * Edim + kk)
                : (W_hh + ((size_t)k * G4H + row) * Hdim + (kk - Edim));
            float4 lo = *(const float4*)p;
            float4 hi = *(const float4*)(p + 4);
            *(bf16x8*)(WF + ((size_t)(((k * 4 + hq) * 12 + st) * 16 + idx) * 64 + l) * 8) = cvt8(lo, hi);
        }
    } else if (b < NWF + NXF) {
        // ---- LSTM X fragments (gathered rows): (k, s) ----
        int b2 = b - NWF; int k = b2 >> 3; int s = b2 & 7;
        int cntk = ws[k];
        int rc = min(64, cntk - s * 64);
        if (rc <= 0) return;
        int m = sub;
        int j = m * 16 + c16;
        int jj = min(j, rc - 1);
        int orig = ws[RK_OFF + k * SK + s * 64 + jj];
        #pragma unroll
        for (int st = 0; st < 12; st++) {
            int kk = st * 32 + qd * 8;
            const float* p = (st < 4) ? inp + (size_t)orig * Edim + kk
                                      : h_prev + (size_t)orig * Hdim + (kk - Edim);
            float4 lo = *(const float4*)p;
            float4 hi = *(const float4*)(p + 4);
            *(bf16x8*)(XF + ((size_t)(((k * 8 + s) * 12 + st) * 4 + m) * 64 + l) * 8) = cvt8(lo, hi);
        }
    } else if (b < NWF + NXF + NLF) {
        // ---- loss weight fragments: (c, st), 80 logit rows (64 Wlin + 2 Wec + 5 Wrel + 9 pad) ----
        int b3 = b - NWF - NXF; int c = b3 >> 3; int st = b3 & 7;
        int kk = st * 32 + qd * 8;
        for (int wg = sub; wg < 5; wg += 4) {
            int lr = wg * 16 + c16;
            bf16x8 v;
            if (lr < 71) {
                const float* p;
                if (lr < 64)      p = Wlin + ((size_t)c * Vdim + lr) * Hdim + kk;
                else if (lr < 66) p = Wec + (size_t)(lr - 64) * Hdim + kk;
                else              p = Wrel + (size_t)(lr - 66) * Hdim + kk;
                float4 lo = *(const float4*)p;
                float4 hi = *(const float4*)(p + 4);
                v = cvt8(lo, hi);
            } else {
                v = (bf16x8){0, 0, 0, 0, 0, 0, 0, 0};
            }
            *(bf16x8*)(LF + ((size_t)((c * 8 + st) * 5 + wg) * 64 + l) * 8) = v;
        }
    } else {
        // ---- loss vec fragments (gathered rows): (c, s) ----
        int b4 = b - NWF - NXF - NLF; int c = b4 >> 3; int s = b4 & 7;
        int cntc = ws[32 + c];
        int rc = min(32, cntc - s * 32);
        if (rc <= 0) return;
        int m = sub & 1, sh = sub >> 1;
        int j = m * 16 + c16;
        int jj = min(j, rc - 1);
        int orig = ws[RC_OFF + c * SC + s * 32 + jj];
        #pragma unroll
        for (int q = 0; q < 4; q++) {
            int st = sh * 4 + q;
            int kk = st * 32 + qd * 8;
            const float* p = vec + (size_t)orig * Hdim + kk;
            float4 lo = *(const float4*)p;
            float4 hi = *(const float4*)(p + 4);
            *(bf16x8*)(VF + ((size_t)(((c * 8 + s) * 8 + st) * 2 + m) * 64 + l) * 8) = cvt8(lo, hi);
        }
    }
}

// ================= main: pure fragment-stream + MFMA (no LDS staging, no barriers) =================
__global__ __launch_bounds__(256, 3) void k_main(
    const float* __restrict__ c_prev,
    const float* __restrict__ blin, const float* __restrict__ bec, const float* __restrict__ brel,
    const float* __restrict__ b_ih, const float* __restrict__ b_hh,
    const int* __restrict__ true_idx, const int* __restrict__ ec_idx, const int* __restrict__ rel_idx,
    const int* __restrict__ ws,
    float* __restrict__ out)
{
    const u16* WF = (const u16*)((const char*)ws + OFF_WF);
    const u16* XF = (const u16*)((const char*)ws + OFF_XF);
    const u16* LF = (const u16*)((const char*)ws + OFF_LF);
    const u16* VF = (const u16*)((const char*)ws + OFF_VF);

    int b = blockIdx.x, t = threadIdx.x;
    int wv = t >> 6, l = t & 63;
    int l15 = l & 15, quad = l >> 4;
    __shared__ float Lg[32 * 84];

    if (b < LSTM_BLOCKS) {
        int k = b >> 5; int s = (b >> 2) & 7; int hq = b & 3;
        int cntk = ws[k];
        int rcount = min(64, cntk - s * 64);
        if (rcount <= 0) return;

        const u16* xf = XF + (size_t)((k * 8 + s) * 12) * 2048 + (size_t)l * 8;
        const u16* wf = WF + (size_t)((k * 4 + hq) * 12) * 8192 + (size_t)(wv * 512) + (size_t)l * 8;

        f32x4 acc[4][4];
        #pragma unroll
        for (int m = 0; m < 4; m++)
            #pragma unroll
            for (int g = 0; g < 4; g++)
                acc[m][g] = (f32x4){0.f, 0.f, 0.f, 0.f};

        for (int st = 0; st < 12; st++) {
            const u16* xs = xf + st * 2048;
            const u16* wp = wf + st * 8192;
            bf16x8 af[4], bfr[4];
            #pragma unroll
            for (int m = 0; m < 4; m++) af[m] = *(const bf16x8*)(xs + m * 512);
            #pragma unroll
            for (int g = 0; g < 4; g++) bfr[g] = *(const bf16x8*)(wp + g * 2048);
            #pragma unroll
            for (int m = 0; m < 4; m++)
                #pragma unroll
                for (int g = 0; g < 4; g++)
                    acc[m][g] = __builtin_amdgcn_mfma_f32_16x16x32_bf16(af[m], bfr[g], acc[m][g], 0, 0, 0);
        }

        int h = hq * 64 + wv * 16 + l15;
        float bs[4];
        #pragma unroll
        for (int g = 0; g < 4; g++)
            bs[g] = b_ih[(size_t)k * G4H + g * Hdim + h] + b_hh[(size_t)k * G4H + g * Hdim + h];

        int reg_row = ws[RK_OFF + k * SK + s * 64 + min(l, rcount - 1)];

        #pragma unroll
        for (int m = 0; m < 4; m++) {
            #pragma unroll
            for (int reg = 0; reg < 4; reg++) {
                int r = m * 16 + quad * 4 + reg;
                int row = __shfl(reg_row, r);
                if (r < rcount) {
                    float iv = acc[m][0][reg] + bs[0];
                    float fv = acc[m][1][reg] + bs[1];
                    float gv = acc[m][2][reg] + bs[2];
                    float ov = acc[m][3][reg] + bs[3];
                    float cp = c_prev[(size_t)row * Hdim + h];
                    float cn = sigmoidf_(fv) * cp + sigmoidf_(iv) * tanhf(gv);
                    float hn = sigmoidf_(ov) * tanhf(cn);
                    out[(size_t)row * OUTS + 1 + h] = hn;
                    out[(size_t)row * OUTS + 1 + Hdim + h] = cn;
                }
            }
        }
    } else {
        int b2 = b - LSTM_BLOCKS; int c = b2 >> 3; int s = b2 & 7;
        int cntc = ws[32 + c];
        int rcount = min(32, cntc - s * 32);
        if (rcount <= 0) return;

        const u16* vf = VF + (size_t)((c * 8 + s) * 8) * 1024 + (size_t)l * 8;
        const u16* lf = LF + (size_t)(c * 8) * 2560 + (size_t)l * 8;

        f32x4 a0[2], a1[2];
        #pragma unroll
        for (int m = 0; m < 2; m++) { a0[m] = (f32x4){0.f,0.f,0.f,0.f}; a1[m] = (f32x4){0.f,0.f,0.f,0.f}; }

        for (int st = 0; st < 8; st++) {
            bf16x8 af0 = *(const bf16x8*)(vf + st * 1024);
            bf16x8 af1 = *(const bf16x8*)(vf + st * 1024 + 512);
            bf16x8 b0 = *(const bf16x8*)(lf + st * 2560 + wv * 512);
            a0[0] = __builtin_amdgcn_mfma_f32_16x16x32_bf16(af0, b0, a0[0], 0, 0, 0);
            a0[1] = __builtin_amdgcn_mfma_f32_16x16x32_bf16(af1, b0, a0[1], 0, 0, 0);
            if (wv == 3) {
                bf16x8 b1 = *(const bf16x8*)(lf + st * 2560 + 4 * 512);
                a1[0] = __builtin_amdgcn_mfma_f32_16x16x32_bf16(af0, b1, a1[0], 0, 0, 0);
                a1[1] = __builtin_amdgcn_mfma_f32_16x16x32_bf16(af1, b1, a1[1], 0, 0, 0);
            }
        }

        int reg_row = ws[RC_OFF + c * SC + s * 32 + min(l & 31, rcount - 1)];

        {
            int col = wv * 16 + l15;
            float bb = blin[c * Vdim + col];
            #pragma unroll
            for (int m = 0; m < 2; m++)
                #pragma unroll
                for (int reg = 0; reg < 4; reg++)
                    Lg[(m * 16 + quad * 4 + reg) * 84 + col] = a0[m][reg] + bb;
            if (wv == 3) {
                int col1 = 64 + l15;
                float bb1 = (l15 < 2) ? bec[l15] : ((l15 < 7) ? brel[l15 - 2] : 0.f);
                #pragma unroll
                for (int m = 0; m < 2; m++)
                    #pragma unroll
                    for (int reg = 0; reg < 4; reg++)
                        Lg[(m * 16 + quad * 4 + reg) * 84 + col1] = a1[m][reg] + bb1;
            }
        }
        __syncthreads();
        for (int rr = 0; rr < 8; rr++) {
            int r = wv * 8 + rr;
            if (r >= rcount) break;
            int orig = __shfl(reg_row, r);
            float lg = Lg[r * 84 + l];
            float mx = lg;
            for (int ss = 32; ss >= 1; ss >>= 1) mx = fmaxf(mx, __shfl_xor(mx, ss));
            float sm = expf(lg - mx);
            for (int ss = 32; ss >= 1; ss >>= 1) sm += __shfl_xor(sm, ss);
            float lt = __shfl(lg, true_idx[orig]);
            float loss = mx + logf(sm) - lt;
            if (l == 0) {
                float l0 = Lg[r * 84 + 64], l1 = Lg[r * 84 + 65];
                float me2 = fmaxf(l0, l1);
                loss += me2 + logf(expf(l0 - me2) + expf(l1 - me2)) - ((ec_idx[orig] == 0) ? l0 : l1);
                float rl[5] = { Lg[r * 84 + 66], Lg[r * 84 + 67], Lg[r * 84 + 68], Lg[r * 84 + 69], Lg[r * 84 + 70] };
                float mr = rl[0];
                #pragma unroll
                for (int i = 1; i < 5; i++) mr = fmaxf(mr, rl[i]);
                float sr = 0.f;
                #pragma unroll
                for (int i = 0; i < 5; i++) sr += expf(rl[i] - mr);
                loss += mr + logf(sr) - rl[rel_idx[orig]];
                out[(size_t)orig * OUTS] = loss;
            }
        }
    }
}

extern "C" void kernel_launch(void* const* d_in, const int* in_sizes, int n_in,
                              void* d_out, int out_size, void* d_ws, size_t ws_size,
                              hipStream_t stream) {
    const float* vec      = (const float*)d_in[0];
    const float* inp      = (const float*)d_in[1];
    const float* h_prev   = (const float*)d_in[2];
    const float* c_prev   = (const float*)d_in[3];
    const float* Wlin     = (const float*)d_in[4];
    const float* blin     = (const float*)d_in[5];
    const float* Wec      = (const float*)d_in[6];
    const float* bec      = (const float*)d_in[7];
    const float* Wrel     = (const float*)d_in[8];
    const float* brel     = (const float*)d_in[9];
    const float* W_ih     = (const float*)d_in[10];
    const float* b_ih     = (const float*)d_in[11];
    const float* W_hh     = (const float*)d_in[12];
    const float* b_hh     = (const float*)d_in[13];
    const int*   category = (const int*)d_in[14];
    const int*   cell_id  = (const int*)d_in[15];
    const int*   true_idx = (const int*)d_in[16];
    const int*   ec_idx   = (const int*)d_in[17];
    const int*   rel_idx  = (const int*)d_in[18];
    float* out = (float*)d_out;
    int* ws = (int*)d_ws;

    k_bucket<<<2, 1024, 0, stream>>>(cell_id, category, ws);
    k_frag<<<FRAG_GRID, 256, 0, stream>>>(W_ih, W_hh, Wlin, Wec, Wrel, inp, h_prev, vec, ws);
    k_main<<<MAIN_GRID, 256, 0, stream>>>(c_prev, blin, bec, brel, b_ih, b_hh,
                                          true_idx, ec_idx, rel_idx, ws, out);
}